// Round 1
// baseline (808.797 us; speedup 1.0000x reference)
//
#include <hip/hip_runtime.h>

// Problem constants (match reference setup_inputs)
#define BB 256
#define CC 128
#define TT 4096
#define KK 8
#define DT 512
#define DT4 128  // DT / 4 float4's per window

// out[b,c,k,t] = in[b,c, offsets[b,c,k] + t], t in [0, DT)
// One thread per float4 of output, grid-stride.
__global__ __launch_bounds__(256) void st_sampling_gather(
    const float* __restrict__ in,
    const int* __restrict__ offs,
    float4* __restrict__ out,
    int total_vec) {
  int idx = blockIdx.x * blockDim.x + threadIdx.x;
  int stride = gridDim.x * blockDim.x;
  for (int v = idx; v < total_vec; v += stride) {
    int t4   = v & (DT4 - 1);        // which float4 within the window
    int rest = v >> 7;               // v / DT4
    int k    = rest & (KK - 1);
    int bc   = rest >> 3;            // (b*C + c)
    int off  = offs[bc * KK + k];    // window start in [0, T-DT]
    const float* src = in + bc * TT + off + (t4 << 2);
    float4 r;
    r.x = src[0];
    r.y = src[1];
    r.z = src[2];
    r.w = src[3];
    out[v] = r;
  }
}

extern "C" void kernel_launch(void* const* d_in, const int* in_sizes, int n_in,
                              void* d_out, int out_size, void* d_ws, size_t ws_size,
                              hipStream_t stream) {
  const float* in = (const float*)d_in[0];
  const int* offs = (const int*)d_in[1];
  float4* out = (float4*)d_out;

  const int total_vec = (BB * CC * KK * DT) / 4;  // 33,554,432 float4's
  const int block = 256;
  // ~2048 blocks: 524,288 threads resident, 64 float4 each; grid-stride covers rest.
  const int grid = 2048;

  st_sampling_gather<<<grid, block, 0, stream>>>(in, offs, out, total_vec);
}